// Round 12
// baseline (236.740 us; speedup 1.0000x reference)
//
#include <hip/hip_runtime.h>
#include <hip/hip_bf16.h>
#include <cstdint>
#include <cstddef>

#define NB 8
#define NS 1024
#define NH 1024
#define ND 64

typedef __attribute__((ext_vector_type(8))) short bf8_t;
typedef __attribute__((ext_vector_type(4))) float f32x4;
typedef __attribute__((ext_vector_type(4))) short short4v;

__device__ __forceinline__ short f2bfs(float x) {
    union { __hip_bfloat16 h; short s; } u;
    u.h = __float2bfloat16(x);
    return u.s;
}
__device__ __forceinline__ float bf2f(unsigned short h) {
    return __uint_as_float(((unsigned int)h) << 16);
}
__device__ __forceinline__ bf8_t pack_bf8(float4 a, float4 b) {
    bf8_t r;
    r[0] = f2bfs(a.x); r[1] = f2bfs(a.y); r[2] = f2bfs(a.z); r[3] = f2bfs(a.w);
    r[4] = f2bfs(b.x); r[5] = f2bfs(b.y); r[6] = f2bfs(b.z); r[7] = f2bfs(b.w);
    return r;
}

// ws layout (shorts):
//   qp  [8][1024][64] bf16 (x1/8)        @ QP_OFF
//   kp  [8][1024][64] bf16               @ KP_OFF
//   vpT [8][64][1024] bf16               @ VPT_OFF
//   S1  [8][1024][1024] bf16 (content scores -> weights in place) @ S1_OFF
//   Wt_g [3][64][1024] bf16              @ WT_OFF
#define QP_OFF   0
#define KP_OFF   524288
#define VPT_OFF  1048576
#define S1_OFF   1572864
#define WT_OFF   9961472

// ---------------------------------------------------------------------------
// W transpose+cvt: Wt_g[p][n][k] = bf16(W_p[k][n]). grid (64,3), block 256.
// ---------------------------------------------------------------------------
__global__ __launch_bounds__(256, 8) void wcvt_kernel(
    const float* __restrict__ Wq, const float* __restrict__ Wk,
    const float* __restrict__ Wv, short* __restrict__ wt)
{
    const int p = blockIdx.y;
    const int n = blockIdx.x;
    const float* W = (p == 0) ? Wq : (p == 1) ? Wk : Wv;
    const int k0 = threadIdx.x * 4;
    short4v pk;
    #pragma unroll
    for (int i = 0; i < 4; ++i) pk[i] = f2bfs(W[(size_t)(k0 + i) * ND + n]);
    *(short4v*)&wt[((size_t)p * 64 + n) * 1024 + k0] = pk;
}

// ---------------------------------------------------------------------------
// Projection via MFMA, no staging, k-split across wave pairs.
// grid (256, 3), block 256. p==2 stores vpT.
// ---------------------------------------------------------------------------
__global__ __launch_bounds__(256, 3) void proj_kernel(
    const float* __restrict__ qin, const float* __restrict__ kin, const float* __restrict__ vin,
    const short* __restrict__ wt,
    const float* __restrict__ bq, const float* __restrict__ bk, const float* __restrict__ bv,
    short* __restrict__ ws_s)
{
    __shared__ float red[2][16][68];

    const int p = blockIdx.y;
    const float* A    = (p == 0) ? qin : (p == 1) ? kin : vin;
    const float* bias = (p == 0) ? bq  : (p == 1) ? bk  : bv;

    const int t = threadIdx.x;
    const int wv = t >> 6, l = t & 63, lr = l & 15, lg = l >> 4;
    const int rt = wv >> 1, kh = wv & 1;
    const int rw = blockIdx.x * 32 + rt * 16;

    const short* wtp = wt + ((size_t)p * 64) * 1024 + kh * 512;
    const float* ab  = A + (size_t)(rw + lr) * NH + kh * 512;

    f32x4 acc[4];
    #pragma unroll
    for (int n = 0; n < 4; ++n) acc[n] = (f32x4){0.f, 0.f, 0.f, 0.f};

    #pragma unroll 2
    for (int ch = 0; ch < 4; ++ch) {
        #pragma unroll
        for (int s = 0; s < 4; ++s) {
            const int off = ch * 128 + s * 32 + lg * 8;
            bf8_t af = pack_bf8(*(const float4*)&ab[off], *(const float4*)&ab[off + 4]);
            #pragma unroll
            for (int n = 0; n < 4; ++n) {
                bf8_t bf = *(const bf8_t*)&wtp[(size_t)(n * 16 + lr) * 1024 + off];
                acc[n] = __builtin_amdgcn_mfma_f32_16x16x32_bf16(af, bf, acc[n], 0, 0, 0);
            }
        }
    }

    if (kh) {
        #pragma unroll
        for (int n = 0; n < 4; ++n)
            #pragma unroll
            for (int r = 0; r < 4; ++r)
                red[rt][lg * 4 + r][n * 16 + lr] = acc[n][r];
    }
    __syncthreads();
    if (!kh) {
        if (p < 2) {
            short* dst = ws_s + ((p == 0) ? QP_OFF : KP_OFF);
            const float sc = (p == 0) ? 0.125f : 1.0f;
            #pragma unroll
            for (int n = 0; n < 4; ++n) {
                const float bs = bias[n * 16 + lr];
                #pragma unroll
                for (int r = 0; r < 4; ++r) {
                    float v = acc[n][r] + red[rt][lg * 4 + r][n * 16 + lr] + bs;
                    dst[(size_t)(rw + lg * 4 + r) * ND + n * 16 + lr] = f2bfs(v * sc);
                }
            }
        } else {
            short* vpT = ws_s + VPT_OFF;
            const int b = rw >> 10;
            const int sbase = (rw & 1023) + lg * 4;
            #pragma unroll
            for (int n = 0; n < 4; ++n) {
                const float bs = bias[n * 16 + lr];
                short4v pk;
                #pragma unroll
                for (int r = 0; r < 4; ++r)
                    pk[r] = f2bfs(acc[n][r] + red[rt][lg * 4 + r][n * 16 + lr] + bs);
                *(short4v*)&vpT[((size_t)b * 64 + n * 16 + lr) * NS + sbase] = pk;
            }
        }
    }
}

// ---------------------------------------------------------------------------
// Content scores: S1[b][q][k] = qp_b . kp_b
// grid (16 kblk, 64 qblk), block 256.
// ---------------------------------------------------------------------------
__global__ __launch_bounds__(256, 4) void scores_c_kernel(
    const short* __restrict__ ws_s, short* __restrict__ s1)
{
    const short* qp = ws_s + QP_OFF;
    const short* kp = ws_s + KP_OFF;
    const int t = threadIdx.x;
    const int wv = t >> 6, l = t & 63, lr = l & 15, lg = l >> 4;
    const int q0 = blockIdx.y * 16;
    const int k0 = blockIdx.x * 64 + wv * 16;

    #pragma unroll
    for (int b = 0; b < 8; ++b) {
        const short* ap = &qp[((size_t)b * NS + q0 + lr) * ND + lg * 8];
        const short* bp = &kp[((size_t)b * NS + k0 + lr) * ND + lg * 8];
        bf8_t a0 = *(const bf8_t*)ap;
        bf8_t a1 = *(const bf8_t*)(ap + 32);
        bf8_t b0 = *(const bf8_t*)bp;
        bf8_t b1 = *(const bf8_t*)(bp + 32);
        f32x4 acc = {0.f, 0.f, 0.f, 0.f};
        acc = __builtin_amdgcn_mfma_f32_16x16x32_bf16(a0, b0, acc, 0, 0, 0);
        acc = __builtin_amdgcn_mfma_f32_16x16x32_bf16(a1, b1, acc, 0, 0, 0);
        #pragma unroll
        for (int r = 0; r < 4; ++r)
            s1[((size_t)b * NS + q0 + lg * 4 + r) * NS + k0 + lr] = f2bfs(acc[r]);
    }
}

// ---------------------------------------------------------------------------
// Mega kernel (re-fused): per q row --
//   phase A: kbias stream -> bias scores (MFMA), 2-tile software pipeline
//   phase B: softmax; weights -> s1 (for v1) + Wt LDS (for phase C)
//   phase C: vbias stream -> out (v2 part), 2-block register ping-pong
// grid 1024, block 256, 4 WG/CU.
// ---------------------------------------------------------------------------
__global__ __launch_bounds__(256, 4) void mega_kernel(
    const short* __restrict__ ws_s,
    short* __restrict__ s1,
    const float* __restrict__ kbias,
    const float* __restrict__ vbias,
    const int* __restrict__ mask,
    float* __restrict__ out)
{
    __shared__ __align__(16) short Sb[8][1032];   // bias scores; reused as otile in C
    __shared__ __align__(16) short Wt[8][1024];   // normalized weights [b][k]

    const short* qp = ws_s + QP_OFF;
    const int q = blockIdx.x, t = threadIdx.x;
    const int wv = t >> 6, l = t & 63, lr = l & 15, lg = l >> 4;

    // ---- phase A: S2[b][k] = q_b . kbias[q,k], two k-tiles in flight ----
    {
        const bf8_t aq0 = *(const bf8_t*)&qp[((size_t)(lr & 7) * NS + q) * ND + lg * 8];
        const bf8_t aq1 = *(const bf8_t*)&qp[((size_t)(lr & 7) * NS + q) * ND + 32 + lg * 8];
        const float* kbq = kbias + (size_t)q * NS * ND;

        #pragma unroll
        for (int ith = 0; ith < 8; ++ith) {
            const int k0A = wv * 256 + (2 * ith) * 16;
            const int k0B = k0A + 16;
            const float* kA = &kbq[(size_t)(k0A + lr) * ND + lg * 8];
            const float* kB = &kbq[(size_t)(k0B + lr) * ND + lg * 8];
            // issue all 8 loads before any consumption
            float4 A0 = *(const float4*)kA;
            float4 A1 = *(const float4*)(kA + 4);
            float4 A2 = *(const float4*)(kA + 32);
            float4 A3 = *(const float4*)(kA + 36);
            float4 B0 = *(const float4*)kB;
            float4 B1 = *(const float4*)(kB + 4);
            float4 B2 = *(const float4*)(kB + 32);
            float4 B3 = *(const float4*)(kB + 36);

            f32x4 sA = {0.f, 0.f, 0.f, 0.f};
            sA = __builtin_amdgcn_mfma_f32_16x16x32_bf16(aq0, pack_bf8(A0, A1), sA, 0, 0, 0);
            sA = __builtin_amdgcn_mfma_f32_16x16x32_bf16(aq1, pack_bf8(A2, A3), sA, 0, 0, 0);
            f32x4 sB = {0.f, 0.f, 0.f, 0.f};
            sB = __builtin_amdgcn_mfma_f32_16x16x32_bf16(aq0, pack_bf8(B0, B1), sB, 0, 0, 0);
            sB = __builtin_amdgcn_mfma_f32_16x16x32_bf16(aq1, pack_bf8(B2, B3), sB, 0, 0, 0);

            if (lg < 2) {
                #pragma unroll
                for (int r = 0; r < 4; ++r) {
                    Sb[lg * 4 + r][k0A + lr] = f2bfs(sA[r]);
                    Sb[lg * 4 + r][k0B + lr] = f2bfs(sB[r]);
                }
            }
        }
    }
    __syncthreads();

    // ---- phase B: softmax per b; weights -> s1 (global) + Wt (LDS) ----
    {
        const int b = t >> 5, idx = t & 31;
        const int kk = idx * 32;
        short* r1 = s1 + ((size_t)b * NS + q) * NS + kk;
        const int* mb = mask + b * NS + kk;
        const float LOG2E = 1.4426950408889634f;

        float x[32];
        float m = -3.0e38f;
        #pragma unroll
        for (int c = 0; c < 4; ++c) {
            uint4 a4 = *(const uint4*)&r1[8 * c];
            uint4 b4 = *(const uint4*)&Sb[b][kk + 8 * c];
            int4 m0 = *(const int4*)&mb[8 * c];
            int4 m1 = *(const int4*)&mb[8 * c + 4];
            const unsigned short* ap = (const unsigned short*)&a4;
            const unsigned short* bp = (const unsigned short*)&b4;
            const int* mp = (const int*)&m0;
            const int* mq = (const int*)&m1;
            #pragma unroll
            for (int j = 0; j < 8; ++j) {
                float v = bf2f(ap[j]) + bf2f(bp[j]);
                const int mvv = (j < 4) ? mp[j] : mq[j - 4];
                v = (mvv == 0) ? -1e9f : v;
                x[8 * c + j] = v;
                m = fmaxf(m, v);
            }
        }
        #pragma unroll
        for (int off = 1; off < 32; off <<= 1) m = fmaxf(m, __shfl_xor(m, off, 32));

        float lsum = 0.f;
        #pragma unroll
        for (int j = 0; j < 32; ++j) { x[j] = exp2f((x[j] - m) * LOG2E); lsum += x[j]; }
        #pragma unroll
        for (int off = 1; off < 32; off <<= 1) lsum += __shfl_xor(lsum, off, 32);
        const float il = 1.0f / fmaxf(lsum, 1e-30f);

        unsigned short wv16[32];
        #pragma unroll
        for (int j = 0; j < 32; ++j) wv16[j] = (unsigned short)f2bfs(x[j] * il);

        #pragma unroll
        for (int c = 0; c < 4; ++c) {
            *(uint4*)&r1[8 * c]         = *(const uint4*)&wv16[8 * c];
            *(uint4*)&Wt[b][kk + 8 * c] = *(const uint4*)&wv16[8 * c];
        }
    }
    __syncthreads();

    // ---- phase C: out_v2[b][q][:] = sum_k w[b,k] * vbias[q,k,:] ----
    // 2-deep register ping-pong: next block's loads issued before this
    // block's FMAs. Fully static indexing (full unroll).
    float* otile = (float*)&Sb[0][0];   // [4][8][64] f32 = 8 KB, aliases Sb
    {
        const int kq = l >> 4, dq = l & 15;
        const int kw = wv * 256;
        const float* vbq = vbias + (size_t)q * NS * ND;

        float4 av[8];
        #pragma unroll
        for (int b = 0; b < 8; ++b) av[b] = make_float4(0.f, 0.f, 0.f, 0.f);

        // prologue: block 0
        short4v w4A[8];
        float4  vbA[4];
        {
            const int kb = kw + kq * 4;
            #pragma unroll
            for (int b = 0; b < 8; ++b) w4A[b] = *(const short4v*)&Wt[b][kb];
            #pragma unroll
            for (int j = 0; j < 4; ++j)
                vbA[j] = *(const float4*)&vbq[(size_t)(kb + j) * ND + 4 * dq];
        }

        #pragma unroll
        for (int i = 0; i < 16; ++i) {
            short4v w4B[8];
            float4  vbB[4];
            if (i < 15) {
                const int kb2 = kw + (i + 1) * 16 + kq * 4;
                #pragma unroll
                for (int b = 0; b < 8; ++b) w4B[b] = *(const short4v*)&Wt[b][kb2];
                #pragma unroll
                for (int j = 0; j < 4; ++j)
                    vbB[j] = *(const float4*)&vbq[(size_t)(kb2 + j) * ND + 4 * dq];
            }
            #pragma unroll
            for (int j = 0; j < 4; ++j) {
                #pragma unroll
                for (int b = 0; b < 8; ++b) {
                    const float wgt = bf2f((unsigned short)w4A[b][j]);
                    av[b].x += wgt * vbA[j].x; av[b].y += wgt * vbA[j].y;
                    av[b].z += wgt * vbA[j].z; av[b].w += wgt * vbA[j].w;
                }
            }
            if (i < 15) {
                #pragma unroll
                for (int b = 0; b < 8; ++b) w4A[b] = w4B[b];
                #pragma unroll
                for (int j = 0; j < 4; ++j) vbA[j] = vbB[j];
            }
        }

        #pragma unroll
        for (int b = 0; b < 8; ++b) {
            #pragma unroll
            for (int off = 16; off <= 32; off <<= 1) {
                av[b].x += __shfl_xor(av[b].x, off, 64);
                av[b].y += __shfl_xor(av[b].y, off, 64);
                av[b].z += __shfl_xor(av[b].z, off, 64);
                av[b].w += __shfl_xor(av[b].w, off, 64);
            }
        }
        if (l < 16) {
            #pragma unroll
            for (int b = 0; b < 8; ++b)
                *(float4*)&otile[((size_t)wv * 8 + b) * 64 + 4 * l] = av[b];
        }
    }
    __syncthreads();

    if (t < 128) {
        const int b = t >> 4, dd = (t & 15) * 4;
        float4 s = make_float4(0.f, 0.f, 0.f, 0.f);
        #pragma unroll
        for (int w4i = 0; w4i < 4; ++w4i) {
            float4 r = *(const float4*)&otile[((size_t)w4i * 8 + b) * 64 + dd];
            s.x += r.x; s.y += r.y; s.z += r.z; s.w += r.w;
        }
        *(float4*)&out[((size_t)b * NS + q) * ND + dd] = s;
    }
}

// ---------------------------------------------------------------------------
// values_1: out[b][q][d] += W[b] @ vpT[b]  (MFMA, RMW -- runs after mega)
// grid (64 qblk, 8 b), block 256.
// ---------------------------------------------------------------------------
__global__ __launch_bounds__(256, 2) void v1_kernel(
    const short* __restrict__ ws_s, const short* __restrict__ w,
    float* __restrict__ out)
{
    const short* vpT = ws_s + VPT_OFF;
    const int t = threadIdx.x, wv = t >> 6, l = t & 63, lr = l & 15, lg = l >> 4;
    const int b = blockIdx.y;
    const int q0 = blockIdx.x * 16;

    f32x4 acc[4];
    #pragma unroll
    for (int j = 0; j < 4; ++j) acc[j] = (f32x4){0.f, 0.f, 0.f, 0.f};

    const short* arow = &w[((size_t)b * NS + q0 + lr) * NS + lg * 8];
    const short* brow = &vpT[((size_t)b * ND + wv * 16 + lr) * NS + lg * 8];
    #pragma unroll 8
    for (int ch = 0; ch < 32; ++ch) {
        bf8_t a  = *(const bf8_t*)(arow + ch * 32);
        bf8_t bb = *(const bf8_t*)(brow + ch * 32);
        acc[ch & 3] = __builtin_amdgcn_mfma_f32_16x16x32_bf16(a, bb, acc[ch & 3], 0, 0, 0);
    }
    f32x4 s;
    #pragma unroll
    for (int r = 0; r < 4; ++r) s[r] = acc[0][r] + acc[1][r] + acc[2][r] + acc[3][r];

    #pragma unroll
    for (int r = 0; r < 4; ++r) {
        float* op = &out[((size_t)b * NS + q0 + lg * 4 + r) * ND + wv * 16 + lr];
        *op = *op + s[r];
    }
}

extern "C" void kernel_launch(void* const* d_in, const int* in_sizes, int n_in,
                              void* d_out, int out_size, void* d_ws, size_t ws_size,
                              hipStream_t stream) {
    (void)in_sizes; (void)n_in; (void)out_size; (void)ws_size;
    const float* query = (const float*)d_in[0];
    const float* key   = (const float*)d_in[1];
    const float* value = (const float*)d_in[2];
    const float* Wq    = (const float*)d_in[3];
    const float* bq    = (const float*)d_in[4];
    const float* Wk    = (const float*)d_in[5];
    const float* bk    = (const float*)d_in[6];
    const float* Wv    = (const float*)d_in[7];
    const float* bv    = (const float*)d_in[8];
    const float* kbias = (const float*)d_in[9];
    const float* vbias = (const float*)d_in[10];
    const int*   mask  = (const int*)d_in[11];
    short* ws_s = (short*)d_ws;
    short* s1 = ws_s + S1_OFF;
    short* wt = ws_s + WT_OFF;
    float* outp = (float*)d_out;

    wcvt_kernel<<<dim3(64, 3), 256, 0, stream>>>(Wq, Wk, Wv, wt);
    proj_kernel<<<dim3(256, 3), 256, 0, stream>>>(query, key, value, wt, bq, bk, bv, ws_s);
    scores_c_kernel<<<dim3(16, 64), 256, 0, stream>>>(ws_s, s1);
    mega_kernel<<<1024, 256, 0, stream>>>(ws_s, s1, kbias, vbias, mask, outp);
    v1_kernel<<<dim3(64, 8), 256, 0, stream>>>(ws_s, s1, outp);
}

// Round 13
// 195.600 us; speedup vs baseline: 1.2103x; 1.2103x over previous
//
#include <hip/hip_runtime.h>
#include <hip/hip_bf16.h>
#include <cstdint>
#include <cstddef>

#define NB 8
#define NS 1024
#define NH 1024
#define ND 64

typedef __attribute__((ext_vector_type(8))) short bf8_t;
typedef __attribute__((ext_vector_type(4))) float f32x4;
typedef __attribute__((ext_vector_type(4))) short short4v;

__device__ __forceinline__ short f2bfs(float x) {
    union { __hip_bfloat16 h; short s; } u;
    u.h = __float2bfloat16(x);
    return u.s;
}
__device__ __forceinline__ float bf2f(unsigned short h) {
    return __uint_as_float(((unsigned int)h) << 16);
}
__device__ __forceinline__ bf8_t pack_bf8(float4 a, float4 b) {
    bf8_t r;
    r[0] = f2bfs(a.x); r[1] = f2bfs(a.y); r[2] = f2bfs(a.z); r[3] = f2bfs(a.w);
    r[4] = f2bfs(b.x); r[5] = f2bfs(b.y); r[6] = f2bfs(b.z); r[7] = f2bfs(b.w);
    return r;
}

// ws layout (shorts):
//   qp  [8][1024][64] bf16 (x1/8)        @ QP_OFF
//   kp  [8][1024][64] bf16               @ KP_OFF
//   vpT [8][64][1024] bf16               @ VPT_OFF
//   S1  [8][1024][1024] bf16 (content scores -> weights in place) @ S1_OFF
//   Wt_g [3][64][1024] bf16              @ WT_OFF
#define QP_OFF   0
#define KP_OFF   524288
#define VPT_OFF  1048576
#define S1_OFF   1572864
#define WT_OFF   9961472

// ---------------------------------------------------------------------------
// W transpose+cvt: Wt_g[p][n][k] = bf16(W_p[k][n]). grid (64,3), block 256.
// ---------------------------------------------------------------------------
__global__ __launch_bounds__(256, 8) void wcvt_kernel(
    const float* __restrict__ Wq, const float* __restrict__ Wk,
    const float* __restrict__ Wv, short* __restrict__ wt)
{
    const int p = blockIdx.y;
    const int n = blockIdx.x;
    const float* W = (p == 0) ? Wq : (p == 1) ? Wk : Wv;
    const int k0 = threadIdx.x * 4;
    short4v pk;
    #pragma unroll
    for (int i = 0; i < 4; ++i) pk[i] = f2bfs(W[(size_t)(k0 + i) * ND + n]);
    *(short4v*)&wt[((size_t)p * 64 + n) * 1024 + k0] = pk;
}

// ---------------------------------------------------------------------------
// Projection via MFMA, no staging, k-split across wave pairs.
// grid (256, 3), block 256. p==2 stores vpT.
// ---------------------------------------------------------------------------
__global__ __launch_bounds__(256, 3) void proj_kernel(
    const float* __restrict__ qin, const float* __restrict__ kin, const float* __restrict__ vin,
    const short* __restrict__ wt,
    const float* __restrict__ bq, const float* __restrict__ bk, const float* __restrict__ bv,
    short* __restrict__ ws_s)
{
    __shared__ float red[2][16][68];

    const int p = blockIdx.y;
    const float* A    = (p == 0) ? qin : (p == 1) ? kin : vin;
    const float* bias = (p == 0) ? bq  : (p == 1) ? bk  : bv;

    const int t = threadIdx.x;
    const int wv = t >> 6, l = t & 63, lr = l & 15, lg = l >> 4;
    const int rt = wv >> 1, kh = wv & 1;
    const int rw = blockIdx.x * 32 + rt * 16;

    const short* wtp = wt + ((size_t)p * 64) * 1024 + kh * 512;
    const float* ab  = A + (size_t)(rw + lr) * NH + kh * 512;

    f32x4 acc[4];
    #pragma unroll
    for (int n = 0; n < 4; ++n) acc[n] = (f32x4){0.f, 0.f, 0.f, 0.f};

    #pragma unroll 2
    for (int ch = 0; ch < 4; ++ch) {
        #pragma unroll
        for (int s = 0; s < 4; ++s) {
            const int off = ch * 128 + s * 32 + lg * 8;
            bf8_t af = pack_bf8(*(const float4*)&ab[off], *(const float4*)&ab[off + 4]);
            #pragma unroll
            for (int n = 0; n < 4; ++n) {
                bf8_t bf = *(const bf8_t*)&wtp[(size_t)(n * 16 + lr) * 1024 + off];
                acc[n] = __builtin_amdgcn_mfma_f32_16x16x32_bf16(af, bf, acc[n], 0, 0, 0);
            }
        }
    }

    if (kh) {
        #pragma unroll
        for (int n = 0; n < 4; ++n)
            #pragma unroll
            for (int r = 0; r < 4; ++r)
                red[rt][lg * 4 + r][n * 16 + lr] = acc[n][r];
    }
    __syncthreads();
    if (!kh) {
        if (p < 2) {
            short* dst = ws_s + ((p == 0) ? QP_OFF : KP_OFF);
            const float sc = (p == 0) ? 0.125f : 1.0f;
            #pragma unroll
            for (int n = 0; n < 4; ++n) {
                const float bs = bias[n * 16 + lr];
                #pragma unroll
                for (int r = 0; r < 4; ++r) {
                    float v = acc[n][r] + red[rt][lg * 4 + r][n * 16 + lr] + bs;
                    dst[(size_t)(rw + lg * 4 + r) * ND + n * 16 + lr] = f2bfs(v * sc);
                }
            }
        } else {
            short* vpT = ws_s + VPT_OFF;
            const int b = rw >> 10;
            const int sbase = (rw & 1023) + lg * 4;
            #pragma unroll
            for (int n = 0; n < 4; ++n) {
                const float bs = bias[n * 16 + lr];
                short4v pk;
                #pragma unroll
                for (int r = 0; r < 4; ++r)
                    pk[r] = f2bfs(acc[n][r] + red[rt][lg * 4 + r][n * 16 + lr] + bs);
                *(short4v*)&vpT[((size_t)b * 64 + n * 16 + lr) * NS + sbase] = pk;
            }
        }
    }
}

// ---------------------------------------------------------------------------
// Content scores: S1[b][q][k] = qp_b . kp_b
// grid (16 kblk, 64 qblk), block 256.
// ---------------------------------------------------------------------------
__global__ __launch_bounds__(256, 4) void scores_c_kernel(
    const short* __restrict__ ws_s, short* __restrict__ s1)
{
    const short* qp = ws_s + QP_OFF;
    const short* kp = ws_s + KP_OFF;
    const int t = threadIdx.x;
    const int wv = t >> 6, l = t & 63, lr = l & 15, lg = l >> 4;
    const int q0 = blockIdx.y * 16;
    const int k0 = blockIdx.x * 64 + wv * 16;

    #pragma unroll
    for (int b = 0; b < 8; ++b) {
        const short* ap = &qp[((size_t)b * NS + q0 + lr) * ND + lg * 8];
        const short* bp = &kp[((size_t)b * NS + k0 + lr) * ND + lg * 8];
        bf8_t a0 = *(const bf8_t*)ap;
        bf8_t a1 = *(const bf8_t*)(ap + 32);
        bf8_t b0 = *(const bf8_t*)bp;
        bf8_t b1 = *(const bf8_t*)(bp + 32);
        f32x4 acc = {0.f, 0.f, 0.f, 0.f};
        acc = __builtin_amdgcn_mfma_f32_16x16x32_bf16(a0, b0, acc, 0, 0, 0);
        acc = __builtin_amdgcn_mfma_f32_16x16x32_bf16(a1, b1, acc, 0, 0, 0);
        #pragma unroll
        for (int r = 0; r < 4; ++r)
            s1[((size_t)b * NS + q0 + lg * 4 + r) * NS + k0 + lr] = f2bfs(acc[r]);
    }
}

// ---------------------------------------------------------------------------
// Mega kernel: per q row. LDS cut to 24.7 KB (weights overwrite bias scores
// in place) -> 6 WG/CU (24 waves). R6 phase structure otherwise.
//   A: kbias stream -> bias scores (MFMA) -> Sb
//   B: softmax(S1 + Sb, mask); weights -> s1 (global, for v1) + Sb in place
//   C: vbias stream, weights from Sb -> out (v2 part)
// grid 1024, block 256, 6 WG/CU.
// ---------------------------------------------------------------------------
__global__ __launch_bounds__(256, 6) void mega_kernel(
    const short* __restrict__ ws_s,
    short* __restrict__ s1,
    const float* __restrict__ kbias,
    const float* __restrict__ vbias,
    const int* __restrict__ mask,
    float* __restrict__ out)
{
    __shared__ __align__(16) short Sb[8][1032];       // bias scores -> weights, 16.5 KB
    __shared__ __align__(16) float otile[4][8][64];   // 8 KB

    const short* qp = ws_s + QP_OFF;
    const int q = blockIdx.x, t = threadIdx.x;
    const int wv = t >> 6, l = t & 63, lr = l & 15, lg = l >> 4;

    // ---- phase A: bias scores S2[b][k] = q_b . kbias[q,k] via MFMA ----
    {
        const bf8_t aq0 = *(const bf8_t*)&qp[((size_t)(lr & 7) * NS + q) * ND + lg * 8];
        const bf8_t aq1 = *(const bf8_t*)&qp[((size_t)(lr & 7) * NS + q) * ND + 32 + lg * 8];
        const float* kbq = kbias + (size_t)q * NS * ND;

        #pragma unroll 4
        for (int it = 0; it < 16; ++it) {
            const int k0 = wv * 256 + it * 16;
            const float* kb = &kbq[(size_t)(k0 + lr) * ND + lg * 8];
            bf8_t b0 = pack_bf8(*(const float4*)kb, *(const float4*)(kb + 4));
            bf8_t b1 = pack_bf8(*(const float4*)(kb + 32), *(const float4*)(kb + 36));
            f32x4 acc = {0.f, 0.f, 0.f, 0.f};
            acc = __builtin_amdgcn_mfma_f32_16x16x32_bf16(aq0, b0, acc, 0, 0, 0);
            acc = __builtin_amdgcn_mfma_f32_16x16x32_bf16(aq1, b1, acc, 0, 0, 0);
            if (lg < 2) {
                #pragma unroll
                for (int r = 0; r < 4; ++r)
                    Sb[lg * 4 + r][k0 + lr] = f2bfs(acc[r]);
            }
        }
    }
    __syncthreads();

    // ---- phase B: softmax per b; weights -> s1 (global) + Sb (in place) ----
    {
        const int b = t >> 5, idx = t & 31;
        const int kk = idx * 32;
        short* r1 = s1 + ((size_t)b * NS + q) * NS + kk;
        const int* mb = mask + b * NS + kk;
        const float LOG2E = 1.4426950408889634f;

        float x[32];
        float m = -3.0e38f;
        #pragma unroll
        for (int c = 0; c < 4; ++c) {
            uint4 a4 = *(const uint4*)&r1[8 * c];
            uint4 b4 = *(const uint4*)&Sb[b][kk + 8 * c];
            int4 m0 = *(const int4*)&mb[8 * c];
            int4 m1 = *(const int4*)&mb[8 * c + 4];
            const unsigned short* ap = (const unsigned short*)&a4;
            const unsigned short* bp = (const unsigned short*)&b4;
            const int* mp = (const int*)&m0;
            const int* mq = (const int*)&m1;
            #pragma unroll
            for (int j = 0; j < 8; ++j) {
                float v = bf2f(ap[j]) + bf2f(bp[j]);
                const int mvv = (j < 4) ? mp[j] : mq[j - 4];
                v = (mvv == 0) ? -1e9f : v;
                x[8 * c + j] = v;
                m = fmaxf(m, v);
            }
        }
        #pragma unroll
        for (int off = 1; off < 32; off <<= 1) m = fmaxf(m, __shfl_xor(m, off, 32));

        float lsum = 0.f;
        #pragma unroll
        for (int j = 0; j < 32; ++j) { x[j] = exp2f((x[j] - m) * LOG2E); lsum += x[j]; }
        #pragma unroll
        for (int off = 1; off < 32; off <<= 1) lsum += __shfl_xor(lsum, off, 32);
        const float il = 1.0f / fmaxf(lsum, 1e-30f);

        unsigned short wv16[32];
        #pragma unroll
        for (int j = 0; j < 32; ++j) wv16[j] = (unsigned short)f2bfs(x[j] * il);

        #pragma unroll
        for (int c = 0; c < 4; ++c) {
            *(uint4*)&r1[8 * c]         = *(const uint4*)&wv16[8 * c];
            *(uint4*)&Sb[b][kk + 8 * c] = *(const uint4*)&wv16[8 * c];
        }
    }
    __syncthreads();

    // ---- phase C: out_v2[b][q][:] = sum_k w[b,k] * vbias[q,k,:] ----
    {
        const int kq = l >> 4, dq = l & 15;
        const int kw = wv * 256;
        const float* vbq = vbias + (size_t)q * NS * ND;

        float4 av[8];
        #pragma unroll
        for (int b = 0; b < 8; ++b) av[b] = make_float4(0.f, 0.f, 0.f, 0.f);

        #pragma unroll 2
        for (int i = 0; i < 64; ++i) {
            const int k = kw + kq + 4 * i;
            const float4 vb = *(const float4*)&vbq[(size_t)k * ND + 4 * dq];
            #pragma unroll
            for (int b = 0; b < 8; ++b) {
                const float wgt = bf2f((unsigned short)Sb[b][k]);
                av[b].x += wgt * vb.x; av[b].y += wgt * vb.y;
                av[b].z += wgt * vb.z; av[b].w += wgt * vb.w;
            }
        }
        #pragma unroll
        for (int b = 0; b < 8; ++b) {
            #pragma unroll
            for (int off = 16; off <= 32; off <<= 1) {
                av[b].x += __shfl_xor(av[b].x, off, 64);
                av[b].y += __shfl_xor(av[b].y, off, 64);
                av[b].z += __shfl_xor(av[b].z, off, 64);
                av[b].w += __shfl_xor(av[b].w, off, 64);
            }
        }
        if (l < 16) {
            #pragma unroll
            for (int b = 0; b < 8; ++b)
                *(float4*)&otile[wv][b][4 * l] = av[b];
        }
    }
    __syncthreads();

    if (t < 128) {
        const int b = t >> 4, dd = (t & 15) * 4;
        float4 s = make_float4(0.f, 0.f, 0.f, 0.f);
        #pragma unroll
        for (int w4i = 0; w4i < 4; ++w4i) {
            float4 r = *(const float4*)&otile[w4i][b][dd];
            s.x += r.x; s.y += r.y; s.z += r.z; s.w += r.w;
        }
        *(float4*)&out[((size_t)b * NS + q) * ND + dd] = s;
    }
}

// ---------------------------------------------------------------------------
// values_1: out[b][q][d] += W[b] @ vpT[b]  (MFMA, RMW -- runs after mega)
// grid (64 qblk, 8 b), block 256.
// ---------------------------------------------------------------------------
__global__ __launch_bounds__(256, 2) void v1_kernel(
    const short* __restrict__ ws_s, const short* __restrict__ w,
    float* __restrict__ out)
{
    const short* vpT = ws_s + VPT_OFF;
    const int t = threadIdx.x, wv = t >> 6, l = t & 63, lr = l & 15, lg = l >> 4;
    const int b = blockIdx.y;
    const int q0 = blockIdx.x * 16;

    f32x4 acc[4];
    #pragma unroll
    for (int j = 0; j < 4; ++j) acc[j] = (f32x4){0.f, 0.f, 0.f, 0.f};

    const short* arow = &w[((size_t)b * NS + q0 + lr) * NS + lg * 8];
    const short* brow = &vpT[((size_t)b * ND + wv * 16 + lr) * NS + lg * 8];
    #pragma unroll 8
    for (int ch = 0; ch < 32; ++ch) {
        bf8_t a  = *(const bf8_t*)(arow + ch * 32);
        bf8_t bb = *(const bf8_t*)(brow + ch * 32);
        acc[ch & 3] = __builtin_amdgcn_mfma_f32_16x16x32_bf16(a, bb, acc[ch & 3], 0, 0, 0);
    }
    f32x4 s;
    #pragma unroll
    for (int r = 0; r < 4; ++r) s[r] = acc[0][r] + acc[1][r] + acc[2][r] + acc[3][r];

    #pragma unroll
    for (int r = 0; r < 4; ++r) {
        float* op = &out[((size_t)b * NS + q0 + lg * 4 + r) * ND + wv * 16 + lr];
        *op = *op + s[r];
    }
}

extern "C" void kernel_launch(void* const* d_in, const int* in_sizes, int n_in,
                              void* d_out, int out_size, void* d_ws, size_t ws_size,
                              hipStream_t stream) {
    (void)in_sizes; (void)n_in; (void)out_size; (void)ws_size;
    const float* query = (const float*)d_in[0];
    const float* key   = (const float*)d_in[1];
    const float* value = (const float*)d_in[2];
    const float* Wq    = (const float*)d_in[3];
    const float* bq    = (const float*)d_in[4];
    const float* Wk    = (const float*)d_in[5];
    const float* bk    = (const float*)d_in[6];
    const float* Wv    = (const float*)d_in[7];
    const float* bv    = (const float*)d_in[8];
    const float* kbias = (const float*)d_in[9];
    const float* vbias = (const float*)d_in[10];
    const int*   mask  = (const int*)d_in[11];
    short* ws_s = (short*)d_ws;
    short* s1 = ws_s + S1_OFF;
    short* wt = ws_s + WT_OFF;
    float* outp = (float*)d_out;

    wcvt_kernel<<<dim3(64, 3), 256, 0, stream>>>(Wq, Wk, Wv, wt);
    proj_kernel<<<dim3(256, 3), 256, 0, stream>>>(query, key, value, wt, bq, bk, bv, ws_s);
    scores_c_kernel<<<dim3(16, 64), 256, 0, stream>>>(ws_s, s1);
    mega_kernel<<<1024, 256, 0, stream>>>(ws_s, s1, kbias, vbias, mask, outp);
    v1_kernel<<<dim3(64, 8), 256, 0, stream>>>(ws_s, s1, outp);
}

// Round 14
// 192.934 us; speedup vs baseline: 1.2270x; 1.0138x over previous
//
#include <hip/hip_runtime.h>
#include <hip/hip_bf16.h>
#include <cstdint>
#include <cstddef>

#define NB 8
#define NS 1024
#define NH 1024
#define ND 64

typedef __attribute__((ext_vector_type(8))) short bf8_t;
typedef __attribute__((ext_vector_type(4))) float f32x4;
typedef __attribute__((ext_vector_type(4))) short short4v;

__device__ __forceinline__ short f2bfs(float x) {
    union { __hip_bfloat16 h; short s; } u;
    u.h = __float2bfloat16(x);
    return u.s;
}
__device__ __forceinline__ float bf2f(unsigned short h) {
    return __uint_as_float(((unsigned int)h) << 16);
}
__device__ __forceinline__ bf8_t pack_bf8(float4 a, float4 b) {
    bf8_t r;
    r[0] = f2bfs(a.x); r[1] = f2bfs(a.y); r[2] = f2bfs(a.z); r[3] = f2bfs(a.w);
    r[4] = f2bfs(b.x); r[5] = f2bfs(b.y); r[6] = f2bfs(b.z); r[7] = f2bfs(b.w);
    return r;
}

// ws layout (shorts):
//   qp  [8][1024][64] bf16 (x1/8)        @ QP_OFF
//   kp  [8][1024][64] bf16               @ KP_OFF
//   vpT [8][64][1024] bf16               @ VPT_OFF
//   S1  [8][1024][1024] bf16 (content scores -> weights in place) @ S1_OFF
//   Wt_g [3][64][1024] bf16              @ WT_OFF
#define QP_OFF   0
#define KP_OFF   524288
#define VPT_OFF  1048576
#define S1_OFF   1572864
#define WT_OFF   9961472

// ---------------------------------------------------------------------------
// W transpose+cvt: Wt_g[p][n][k] = bf16(W_p[k][n]). grid (64,3), block 256.
// ---------------------------------------------------------------------------
__global__ __launch_bounds__(256, 8) void wcvt_kernel(
    const float* __restrict__ Wq, const float* __restrict__ Wk,
    const float* __restrict__ Wv, short* __restrict__ wt)
{
    const int p = blockIdx.y;
    const int n = blockIdx.x;
    const float* W = (p == 0) ? Wq : (p == 1) ? Wk : Wv;
    const int k0 = threadIdx.x * 4;
    short4v pk;
    #pragma unroll
    for (int i = 0; i < 4; ++i) pk[i] = f2bfs(W[(size_t)(k0 + i) * ND + n]);
    *(short4v*)&wt[((size_t)p * 64 + n) * 1024 + k0] = pk;
}

// ---------------------------------------------------------------------------
// Projection via MFMA, no staging, k-split across wave pairs.
// grid (256, 3), block 256. p==2 stores vpT.
// ---------------------------------------------------------------------------
__global__ __launch_bounds__(256, 3) void proj_kernel(
    const float* __restrict__ qin, const float* __restrict__ kin, const float* __restrict__ vin,
    const short* __restrict__ wt,
    const float* __restrict__ bq, const float* __restrict__ bk, const float* __restrict__ bv,
    short* __restrict__ ws_s)
{
    __shared__ float red[2][16][68];

    const int p = blockIdx.y;
    const float* A    = (p == 0) ? qin : (p == 1) ? kin : vin;
    const float* bias = (p == 0) ? bq  : (p == 1) ? bk  : bv;

    const int t = threadIdx.x;
    const int wv = t >> 6, l = t & 63, lr = l & 15, lg = l >> 4;
    const int rt = wv >> 1, kh = wv & 1;
    const int rw = blockIdx.x * 32 + rt * 16;

    const short* wtp = wt + ((size_t)p * 64) * 1024 + kh * 512;
    const float* ab  = A + (size_t)(rw + lr) * NH + kh * 512;

    f32x4 acc[4];
    #pragma unroll
    for (int n = 0; n < 4; ++n) acc[n] = (f32x4){0.f, 0.f, 0.f, 0.f};

    #pragma unroll 2
    for (int ch = 0; ch < 4; ++ch) {
        #pragma unroll
        for (int s = 0; s < 4; ++s) {
            const int off = ch * 128 + s * 32 + lg * 8;
            bf8_t af = pack_bf8(*(const float4*)&ab[off], *(const float4*)&ab[off + 4]);
            #pragma unroll
            for (int n = 0; n < 4; ++n) {
                bf8_t bf = *(const bf8_t*)&wtp[(size_t)(n * 16 + lr) * 1024 + off];
                acc[n] = __builtin_amdgcn_mfma_f32_16x16x32_bf16(af, bf, acc[n], 0, 0, 0);
            }
        }
    }

    if (kh) {
        #pragma unroll
        for (int n = 0; n < 4; ++n)
            #pragma unroll
            for (int r = 0; r < 4; ++r)
                red[rt][lg * 4 + r][n * 16 + lr] = acc[n][r];
    }
    __syncthreads();
    if (!kh) {
        if (p < 2) {
            short* dst = ws_s + ((p == 0) ? QP_OFF : KP_OFF);
            const float sc = (p == 0) ? 0.125f : 1.0f;
            #pragma unroll
            for (int n = 0; n < 4; ++n) {
                const float bs = bias[n * 16 + lr];
                #pragma unroll
                for (int r = 0; r < 4; ++r) {
                    float v = acc[n][r] + red[rt][lg * 4 + r][n * 16 + lr] + bs;
                    dst[(size_t)(rw + lg * 4 + r) * ND + n * 16 + lr] = f2bfs(v * sc);
                }
            }
        } else {
            short* vpT = ws_s + VPT_OFF;
            const int b = rw >> 10;
            const int sbase = (rw & 1023) + lg * 4;
            #pragma unroll
            for (int n = 0; n < 4; ++n) {
                const float bs = bias[n * 16 + lr];
                short4v pk;
                #pragma unroll
                for (int r = 0; r < 4; ++r)
                    pk[r] = f2bfs(acc[n][r] + red[rt][lg * 4 + r][n * 16 + lr] + bs);
                *(short4v*)&vpT[((size_t)b * 64 + n * 16 + lr) * NS + sbase] = pk;
            }
        }
    }
}

// ---------------------------------------------------------------------------
// Content scores: S1[b][q][k] = qp_b . kp_b
// grid (16 kblk, 64 qblk), block 256.
// ---------------------------------------------------------------------------
__global__ __launch_bounds__(256, 4) void scores_c_kernel(
    const short* __restrict__ ws_s, short* __restrict__ s1)
{
    const short* qp = ws_s + QP_OFF;
    const short* kp = ws_s + KP_OFF;
    const int t = threadIdx.x;
    const int wv = t >> 6, l = t & 63, lr = l & 15, lg = l >> 4;
    const int q0 = blockIdx.y * 16;
    const int k0 = blockIdx.x * 64 + wv * 16;

    #pragma unroll
    for (int b = 0; b < 8; ++b) {
        const short* ap = &qp[((size_t)b * NS + q0 + lr) * ND + lg * 8];
        const short* bp = &kp[((size_t)b * NS + k0 + lr) * ND + lg * 8];
        bf8_t a0 = *(const bf8_t*)ap;
        bf8_t a1 = *(const bf8_t*)(ap + 32);
        bf8_t b0 = *(const bf8_t*)bp;
        bf8_t b1 = *(const bf8_t*)(bp + 32);
        f32x4 acc = {0.f, 0.f, 0.f, 0.f};
        acc = __builtin_amdgcn_mfma_f32_16x16x32_bf16(a0, b0, acc, 0, 0, 0);
        acc = __builtin_amdgcn_mfma_f32_16x16x32_bf16(a1, b1, acc, 0, 0, 0);
        #pragma unroll
        for (int r = 0; r < 4; ++r)
            s1[((size_t)b * NS + q0 + lg * 4 + r) * NS + k0 + lr] = f2bfs(acc[r]);
    }
}

// ---------------------------------------------------------------------------
// Mega kernel: per q row. Burst-issue loads for MLP-level memory parallelism:
//   A: kbias stream, 2 tiles (8 float4) issued per step -> bias scores (MFMA)
//   B: softmax(S1 + Sb, mask); weights -> s1 (global) + Sb in place
//   C: vbias stream, 8 float4 burst per step, weights via ds_read_b128
// grid 1024, block 256, 4 WG/CU (grid-capped anyway).
// ---------------------------------------------------------------------------
__global__ __launch_bounds__(256, 4) void mega_kernel(
    const short* __restrict__ ws_s,
    short* __restrict__ s1,
    const float* __restrict__ kbias,
    const float* __restrict__ vbias,
    const int* __restrict__ mask,
    float* __restrict__ out)
{
    __shared__ __align__(16) short Sb[8][1032];       // bias scores -> weights
    __shared__ __align__(16) float otile[4][8][64];   // 8 KB

    const short* qp = ws_s + QP_OFF;
    const int q = blockIdx.x, t = threadIdx.x;
    const int wv = t >> 6, l = t & 63, lr = l & 15, lg = l >> 4;

    // ---- phase A: S2[b][k] = q_b . kbias[q,k], 2 tiles' loads batched ----
    {
        const bf8_t aq0 = *(const bf8_t*)&qp[((size_t)(lr & 7) * NS + q) * ND + lg * 8];
        const bf8_t aq1 = *(const bf8_t*)&qp[((size_t)(lr & 7) * NS + q) * ND + 32 + lg * 8];
        const float* kbq = kbias + (size_t)q * NS * ND;

        #pragma unroll 2
        for (int ith = 0; ith < 8; ++ith) {
            const int k0A = wv * 256 + ith * 32;
            const int k0B = k0A + 16;
            const float* kA = &kbq[(size_t)(k0A + lr) * ND + lg * 8];
            const float* kB = &kbq[(size_t)(k0B + lr) * ND + lg * 8];
            // burst: all 8 loads issued before any consumption
            float4 A0 = *(const float4*)kA;
            float4 A1 = *(const float4*)(kA + 4);
            float4 A2 = *(const float4*)(kA + 32);
            float4 A3 = *(const float4*)(kA + 36);
            float4 B0 = *(const float4*)kB;
            float4 B1 = *(const float4*)(kB + 4);
            float4 B2 = *(const float4*)(kB + 32);
            float4 B3 = *(const float4*)(kB + 36);

            f32x4 sA = {0.f, 0.f, 0.f, 0.f};
            sA = __builtin_amdgcn_mfma_f32_16x16x32_bf16(aq0, pack_bf8(A0, A1), sA, 0, 0, 0);
            sA = __builtin_amdgcn_mfma_f32_16x16x32_bf16(aq1, pack_bf8(A2, A3), sA, 0, 0, 0);
            f32x4 sB = {0.f, 0.f, 0.f, 0.f};
            sB = __builtin_amdgcn_mfma_f32_16x16x32_bf16(aq0, pack_bf8(B0, B1), sB, 0, 0, 0);
            sB = __builtin_amdgcn_mfma_f32_16x16x32_bf16(aq1, pack_bf8(B2, B3), sB, 0, 0, 0);

            if (lg < 2) {
                #pragma unroll
                for (int r = 0; r < 4; ++r) {
                    Sb[lg * 4 + r][k0A + lr] = f2bfs(sA[r]);
                    Sb[lg * 4 + r][k0B + lr] = f2bfs(sB[r]);
                }
            }
        }
    }
    __syncthreads();

    // ---- phase B: softmax per b; weights -> s1 (global) + Sb (in place) ----
    {
        const int b = t >> 5, idx = t & 31;
        const int kk = idx * 32;
        short* r1 = s1 + ((size_t)b * NS + q) * NS + kk;
        const int* mb = mask + b * NS + kk;
        const float LOG2E = 1.4426950408889634f;

        float x[32];
        float m = -3.0e38f;
        #pragma unroll
        for (int c = 0; c < 4; ++c) {
            uint4 a4 = *(const uint4*)&r1[8 * c];
            uint4 b4 = *(const uint4*)&Sb[b][kk + 8 * c];
            int4 m0 = *(const int4*)&mb[8 * c];
            int4 m1 = *(const int4*)&mb[8 * c + 4];
            const unsigned short* ap = (const unsigned short*)&a4;
            const unsigned short* bp = (const unsigned short*)&b4;
            const int* mp = (const int*)&m0;
            const int* mq = (const int*)&m1;
            #pragma unroll
            for (int j = 0; j < 8; ++j) {
                float v = bf2f(ap[j]) + bf2f(bp[j]);
                const int mvv = (j < 4) ? mp[j] : mq[j - 4];
                v = (mvv == 0) ? -1e9f : v;
                x[8 * c + j] = v;
                m = fmaxf(m, v);
            }
        }
        #pragma unroll
        for (int off = 1; off < 32; off <<= 1) m = fmaxf(m, __shfl_xor(m, off, 32));

        float lsum = 0.f;
        #pragma unroll
        for (int j = 0; j < 32; ++j) { x[j] = exp2f((x[j] - m) * LOG2E); lsum += x[j]; }
        #pragma unroll
        for (int off = 1; off < 32; off <<= 1) lsum += __shfl_xor(lsum, off, 32);
        const float il = 1.0f / fmaxf(lsum, 1e-30f);

        unsigned short wv16[32];
        #pragma unroll
        for (int j = 0; j < 32; ++j) wv16[j] = (unsigned short)f2bfs(x[j] * il);

        #pragma unroll
        for (int c = 0; c < 4; ++c) {
            *(uint4*)&r1[8 * c]         = *(const uint4*)&wv16[8 * c];
            *(uint4*)&Sb[b][kk + 8 * c] = *(const uint4*)&wv16[8 * c];
        }
    }
    __syncthreads();

    // ---- phase C: out_v2[b][q][:] = sum_k w[b,k] * vbias[q,k,:] ----
    // lane owns 8 CONSECUTIVE k per step: 8-float4 load burst + 8 ds_read_b128.
    {
        const int kq = l >> 4, dq = l & 15;
        const int kw = wv * 256;
        const float* vbq = vbias + (size_t)q * NS * ND;

        float4 av[8];
        #pragma unroll
        for (int b = 0; b < 8; ++b) av[b] = make_float4(0.f, 0.f, 0.f, 0.f);

        for (int ii = 0; ii < 8; ++ii) {
            const int kb = kw + ii * 32 + kq * 8;   // 8 consecutive k for this lane
            float4 vb[8];
            #pragma unroll
            for (int j = 0; j < 8; ++j)
                vb[j] = *(const float4*)&vbq[(size_t)(kb + j) * ND + 4 * dq];
            bf8_t w8[8];
            #pragma unroll
            for (int b = 0; b < 8; ++b) w8[b] = *(const bf8_t*)&Sb[b][kb];
            #pragma unroll
            for (int j = 0; j < 8; ++j) {
                #pragma unroll
                for (int b = 0; b < 8; ++b) {
                    const float wgt = bf2f((unsigned short)w8[b][j]);
                    av[b].x += wgt * vb[j].x; av[b].y += wgt * vb[j].y;
                    av[b].z += wgt * vb[j].z; av[b].w += wgt * vb[j].w;
                }
            }
        }
        #pragma unroll
        for (int b = 0; b < 8; ++b) {
            #pragma unroll
            for (int off = 16; off <= 32; off <<= 1) {
                av[b].x += __shfl_xor(av[b].x, off, 64);
                av[b].y += __shfl_xor(av[b].y, off, 64);
                av[b].z += __shfl_xor(av[b].z, off, 64);
                av[b].w += __shfl_xor(av[b].w, off, 64);
            }
        }
        if (l < 16) {
            #pragma unroll
            for (int b = 0; b < 8; ++b)
                *(float4*)&otile[wv][b][4 * l] = av[b];
        }
    }
    __syncthreads();

    if (t < 128) {
        const int b = t >> 4, dd = (t & 15) * 4;
        float4 s = make_float4(0.f, 0.f, 0.f, 0.f);
        #pragma unroll
        for (int w4i = 0; w4i < 4; ++w4i) {
            float4 r = *(const float4*)&otile[w4i][b][dd];
            s.x += r.x; s.y += r.y; s.z += r.z; s.w += r.w;
        }
        *(float4*)&out[((size_t)b * NS + q) * ND + dd] = s;
    }
}

// ---------------------------------------------------------------------------
// values_1: out[b][q][d] += W[b] @ vpT[b]  (MFMA, RMW -- runs after mega)
// grid (64 qblk, 8 b), block 256.
// ---------------------------------------------------------------------------
__global__ __launch_bounds__(256, 2) void v1_kernel(
    const short* __restrict__ ws_s, const short* __restrict__ w,
    float* __restrict__ out)
{
    const short* vpT = ws_s + VPT_OFF;
    const int t = threadIdx.x, wv = t >> 6, l = t & 63, lr = l & 15, lg = l >> 4;
    const int b = blockIdx.y;
    const int q0 = blockIdx.x * 16;

    f32x4 acc[4];
    #pragma unroll
    for (int j = 0; j < 4; ++j) acc[j] = (f32x4){0.f, 0.f, 0.f, 0.f};

    const short* arow = &w[((size_t)b * NS + q0 + lr) * NS + lg * 8];
    const short* brow = &vpT[((size_t)b * ND + wv * 16 + lr) * NS + lg * 8];
    #pragma unroll 8
    for (int ch = 0; ch < 32; ++ch) {
        bf8_t a  = *(const bf8_t*)(arow + ch * 32);
        bf8_t bb = *(const bf8_t*)(brow + ch * 32);
        acc[ch & 3] = __builtin_amdgcn_mfma_f32_16x16x32_bf16(a, bb, acc[ch & 3], 0, 0, 0);
    }
    f32x4 s;
    #pragma unroll
    for (int r = 0; r < 4; ++r) s[r] = acc[0][r] + acc[1][r] + acc[2][r] + acc[3][r];

    #pragma unroll
    for (int r = 0; r < 4; ++r) {
        float* op = &out[((size_t)b * NS + q0 + lg * 4 + r) * ND + wv * 16 + lr];
        *op = *op + s[r];
    }
}

extern "C" void kernel_launch(void* const* d_in, const int* in_sizes, int n_in,
                              void* d_out, int out_size, void* d_ws, size_t ws_size,
                              hipStream_t stream) {
    (void)in_sizes; (void)n_in; (void)out_size; (void)ws_size;
    const float* query = (const float*)d_in[0];
    const float* key   = (const float*)d_in[1];
    const float* value = (const float*)d_in[2];
    const float* Wq    = (const float*)d_in[3];
    const float* bq    = (const float*)d_in[4];
    const float* Wk    = (const float*)d_in[5];
    const float* bk    = (const float*)d_in[6];
    const float* Wv    = (const float*)d_in[7];
    const float* bv    = (const float*)d_in[8];
    const float* kbias = (const float*)d_in[9];
    const float* vbias = (const float*)d_in[10];
    const int*   mask  = (const int*)d_in[11];
    short* ws_s = (short*)d_ws;
    short* s1 = ws_s + S1_OFF;
    short* wt = ws_s + WT_OFF;
    float* outp = (float*)d_out;

    wcvt_kernel<<<dim3(64, 3), 256, 0, stream>>>(Wq, Wk, Wv, wt);
    proj_kernel<<<dim3(256, 3), 256, 0, stream>>>(query, key, value, wt, bq, bk, bv, ws_s);
    scores_c_kernel<<<dim3(16, 64), 256, 0, stream>>>(ws_s, s1);
    mega_kernel<<<1024, 256, 0, stream>>>(ws_s, s1, kbias, vbias, mask, outp);
    v1_kernel<<<dim3(64, 8), 256, 0, stream>>>(ws_s, s1, outp);
}